// Round 5
// baseline (1981.109 us; speedup 1.0000x reference)
//
#include <hip/hip_runtime.h>

// Shapes: BS=256, C=256, H=W=16, HW=256, conv1: 1024->1024 3x3, conv2: 1024->512 3x3,
// cls: 512->512 1x1 (only diagonal of PSROI needed -> 2 dots/pixel).
//
// Workspace layout (bytes):
//   featT  @ 0          : bf16 [256 b][256 p][1024 ch]  = 134217728   (ch: r1|corr1|r2|corr2)
//   out1T  @ 134217728  : bf16 [256 b][256 p][1024 o]   = 134217728
//   W1b    @ 268435456  : bf16 [9][1024][1024]          = 18874368
//   W2b    @ 287309824  : bf16 [9][512][1024]           = 9437184
//   s1     @ 296747008  : f32  [256*256]                = 262144
//   s2     @ 297009152  : f32  [256*256]                = 262144
//   out2T  @ 0 (overlays featT, dead after conv1): bf16 [256][256][512] = 67108864
//
// SWIZZLED STORAGE FORMAT: every bf16 row-major tensor stores each 64B slice
// (4 x 16B chunks) with chunk index XORed by ((row>>1)&3), row = pixel p or
// out-channel o. Conflict-free LDS b128 reads with monotonic gl2lds staging.
// Balance check for 32-row reads (32x32 MFMA frags): over 32 consecutive rows,
// (row&1, chunk-pair) combos are hit exactly 8x per wave -> 8-cyc b128 floor.
//
// r5: conv rebuilt around v_mfma_f32_32x32x16_bf16 (2495 TF ceiling vs 2075) with
// 128x64 per-wave tiles (43.7 FLOP per LDS byte vs 32). r4 PMC showed LDS-read
// pipe ~83% busy vs MFMA ~62% -> both terms attacked. Blocks: 256 thr / 4 waves
// (2M x 2N), tile M=256 x N=128, 2 blocks/CU (VGPR-capped at 8 waves/CU).
// W prefetch depth 2 (3 bufs, buf = tap%3 since 9%3==0); X double-buffered by kc
// parity, staged at tap0. Counted waits: taps 0,1 vmcnt(6); taps>=2 vmcnt(2).

typedef __attribute__((ext_vector_type(8))) __bf16 bf16x8;
typedef __attribute__((ext_vector_type(4))) float f32x4;
typedef __attribute__((ext_vector_type(16))) float f32x16;
typedef unsigned short u16;

template <bool B> struct BC { static constexpr bool value = B; };

__device__ __forceinline__ u16 f2bf(float f) {
  union { float f; unsigned u; } v; v.f = f;
  unsigned u = v.u;
  u += 0x7fffu + ((u >> 16) & 1u);   // RNE
  return (u16)(u >> 16);
}
__device__ __forceinline__ float bf2f(u16 h) {
  union { unsigned u; float f; } v; v.u = ((unsigned)h) << 16;
  return v.f;
}
__device__ __forceinline__ void gl2lds16(const void* g, void* l) {
  __builtin_amdgcn_global_load_lds(
      (__attribute__((address_space(1))) void*)(void*)g,
      (__attribute__((address_space(3))) void*)l, 16, 0, 0);
}

// ---------------------------------------------------------------------------
// Kernel 1: relu + channel-L2-norm scales + bf16 transpose to featT[b][p][ch].
// Stores in swizzled format: ch' = ch ^ (((p>>1)&3)<<3).
__global__ __launch_bounds__(256) void k_norm(const float* __restrict__ f1,
                                              const float* __restrict__ f2,
                                              u16* __restrict__ featT,
                                              float* __restrict__ s1,
                                              float* __restrict__ s2) {
  int bx = blockIdx.x;
  int b = bx >> 2;
  int p0 = (bx & 3) << 6;
  int t = threadIdx.x;
  int p = p0 + (t & 63);
  int cg = t >> 6;
  int sp3 = ((p >> 1) & 3) << 3;
  const float* F1 = f1 + ((size_t)b << 16);
  const float* F2 = f2 + ((size_t)b << 16);
  u16* FT = featT + (((size_t)(b << 8) + p) << 10);
  float ss1 = 0.f, ss2 = 0.f;
  for (int i = 0; i < 64; ++i) {
    int c = (cg << 6) + i;
    float v1 = F1[(c << 8) + p]; v1 = v1 > 0.f ? v1 : 0.f;
    float v2 = F2[(c << 8) + p]; v2 = v2 > 0.f ? v2 : 0.f;
    ss1 += v1 * v1; ss2 += v2 * v2;
    FT[c ^ sp3] = f2bf(v1);
    FT[512 + (c ^ sp3)] = f2bf(v2);
  }
  __shared__ float l1[256], l2[256];
  l1[t] = ss1; l2[t] = ss2;
  __syncthreads();
  if (t < 64) {
    float a = l1[t] + l1[t + 64] + l1[t + 128] + l1[t + 192];
    float c2 = l2[t] + l2[t + 64] + l2[t + 128] + l2[t + 192];
    int pp = (b << 8) + p0 + t;
    s1[pp] = 1.f / fmaxf(sqrtf(a), 1e-12f);
    s2[pp] = 1.f / fmaxf(sqrtf(c2), 1e-12f);
  }
}

// ---------------------------------------------------------------------------
// Kernel 2: weight repack fp32 [O][C][3][3] -> bf16 [tap][O][C], swizzled:
// c' = c ^ (((o>>1)&3)<<3).
__global__ __launch_bounds__(256) void k_wconv(const float* __restrict__ w,
                                               u16* __restrict__ wb, int O, int C) {
  int o = blockIdx.x;
  int t = threadIdx.x;
  int sp3 = ((o >> 1) & 3) << 3;
  const float* src = w + (size_t)o * C * 9;
  for (int c = t; c < C; c += 256) {
    const float* s = src + c * 9;
    float v[9];
#pragma unroll
    for (int i = 0; i < 9; ++i) v[i] = s[i];
#pragma unroll
    for (int tap = 0; tap < 9; ++tap)
      wb[(size_t)tap * O * C + (size_t)o * C + (c ^ sp3)] = f2bf(v[tap]);
  }
}

// ---------------------------------------------------------------------------
// Kernel 3: Gram GEMM G[p1][p2] = sum_c r1[p1][c]*r2[p2][c], scaled epilogue.
// (unchanged from r4; 16x16x32 MFMA, monotonic staging, swizzled read chunk)
__global__ __launch_bounds__(256) void k_corr(u16* featT,
                                              const float* __restrict__ s1,
                                              const float* __restrict__ s2,
                                              float* __restrict__ out) {
  __shared__ alignas(16) u16 Alds[128 * 32];
  __shared__ alignas(16) u16 Blds[128 * 32];
  __shared__ float tb[4][16][66];
  int bx = blockIdx.x;
  int b = bx >> 2;
  int p1b = ((bx >> 1) & 1) << 7;
  int p2b = (bx & 1) << 7;
  int t = threadIdx.x, l = t & 63, w = t >> 6;
  int wm = w >> 1, wn = w & 1, lr = l & 15, lq = l >> 4;
  int srow = (w << 4) + (l >> 2);
  int sq = (l & 3) << 3;                       // monotonic source chunk
  int rsz = ((lq ^ ((lr >> 1) & 3)) << 3);     // swizzled read chunk
  const size_t bbase = (size_t)b << 18;

  f32x4 acc[4][4];
#pragma unroll
  for (int i = 0; i < 4; ++i)
#pragma unroll
    for (int j = 0; j < 4; ++j) acc[i][j] = (f32x4){0.f, 0.f, 0.f, 0.f};

#pragma unroll 1
  for (int kc = 0; kc < 8; ++kc) {
    int c0 = kc << 5;
    const u16* sA = featT + bbase + ((size_t)(p1b + srow) << 10) + (c0 + sq);
    gl2lds16(sA, Alds + ((w << 4) << 5));
    gl2lds16(sA + (64 << 10), Alds + ((64 + (w << 4)) << 5));
    const u16* sB = featT + bbase + ((size_t)(p2b + srow) << 10) + (512 + c0 + sq);
    gl2lds16(sB, Blds + ((w << 4) << 5));
    gl2lds16(sB + (64 << 10), Blds + ((64 + (w << 4)) << 5));
    __syncthreads();
    bf16x8 af[4], bfr[4];
#pragma unroll
    for (int mf = 0; mf < 4; ++mf)
      af[mf] = *(const bf16x8*)(Alds + (((wm << 6) + (mf << 4) + lr) << 5) + rsz);
#pragma unroll
    for (int nf = 0; nf < 4; ++nf)
      bfr[nf] = *(const bf16x8*)(Blds + (((wn << 6) + (nf << 4) + lr) << 5) + rsz);
#pragma unroll
    for (int mf = 0; mf < 4; ++mf)
#pragma unroll
      for (int nf = 0; nf < 4; ++nf)
        acc[mf][nf] = __builtin_amdgcn_mfma_f32_16x16x32_bf16(af[mf], bfr[nf], acc[mf][nf], 0, 0, 0);
    __syncthreads();
  }

  float sc2[4]; int p2g[4];
#pragma unroll
  for (int nf = 0; nf < 4; ++nf) {
    int p2 = p2b + (wn << 6) + (nf << 4) + lr;
    p2g[nf] = p2;
    sc2[nf] = s2[(b << 8) + p2];
  }
  float* corr1 = out + 512;
  float* corr2 = out + 512 + 16777216;
#pragma unroll
  for (int mf = 0; mf < 4; ++mf) {
    float gv[4][4];
#pragma unroll
    for (int r = 0; r < 4; ++r) {
      int p1 = p1b + (wm << 6) + (mf << 4) + (lq << 2) + r;
      float s1v = s1[(b << 8) + p1];
#pragma unroll
      for (int nf = 0; nf < 4; ++nf) gv[nf][r] = acc[mf][nf][r] * s1v * sc2[nf];
    }
#pragma unroll
    for (int r = 0; r < 4; ++r) {
      int p1 = p1b + (wm << 6) + (mf << 4) + (lq << 2) + r;
      int s1p3 = ((p1 >> 1) & 3) << 3;
#pragma unroll
      for (int nf = 0; nf < 4; ++nf) {
        corr2[((size_t)b << 16) + ((size_t)p1 << 8) + p2g[nf]] = gv[nf][r];
        featT[bbase + ((size_t)p1 << 10) + 256 + (p2g[nf] ^ s1p3)] = f2bf(gv[nf][r]);
      }
    }
#pragma unroll
    for (int r = 0; r < 4; ++r)
#pragma unroll
      for (int nf = 0; nf < 4; ++nf)
        tb[w][(lq << 2) + r][(nf << 4) + lr] = gv[nf][r];
#pragma unroll
    for (int j = 0; j < 16; ++j) {
      float v = tb[w][lr][(j << 2) + lq];
      int p2 = p2b + (wn << 6) + (j << 2) + lq;
      int s2p3 = ((p2 >> 1) & 3) << 3;
      int p1 = p1b + (wm << 6) + (mf << 4) + lr;
      corr1[((size_t)b << 16) + ((size_t)p2 << 8) + p1] = v;
      featT[bbase + ((size_t)p2 << 10) + 768 + (p1 ^ s2p3)] = f2bf(v);
    }
  }
}

// ---------------------------------------------------------------------------
// Kernel 4/5: implicit-GEMM 3x3 conv, 32x32x16 MFMA, 128x64 per-wave tiles.
// Block: M=256 (whole image) x N=128 o; 256 threads = 4 waves (2M x 2N).
// A-frag (X): row = lane&31 (pixel), k = 16h + (lane>>5)*8+j.  B-frag (W): same
// with row = o.  C: col = lane&31 (o), row = (reg&3)+8*(reg>>2)+4*(lane>>5).
// W depth-2 prefetch: 3 bufs, read buf tap%3 (9%3==0 -> kc-independent), write
// (tap+2)%3.  X staged at tap0 into kc-parity buffer.  Counted waits (FIFO
// audited): taps 0,1: vmcnt(6); taps>=2: vmcnt(2).  Border: zero-row redirect.
// Epilogue: per-wave LDS transpose -> merged uint4 stores in swizzled format.
template <int O, int OTB>
__global__ __launch_bounds__(256, 2) void k_conv(const u16* __restrict__ X,
                                                 const u16* __restrict__ Wb,
                                                 const float* __restrict__ bias,
                                                 u16* __restrict__ Out) {
  __shared__ alignas(16) u16 Xlds[2][257 * 32];  // rows 0..255 data, row 256 = zeros
  __shared__ alignas(16) u16 Wlds[3][128 * 32];
  int bx = blockIdx.x;
  int otile = bx & ((1 << OTB) - 1);   // low bits -> XCD affinity for the W slice
  int b = bx >> OTB;
  int t = threadIdx.x, l = t & 63, w = t >> 6;   // 4 waves
  int wm = w >> 1, wn = w & 1;
  int l31 = l & 31, l5 = l >> 5, px = l & 15;
  int o0 = otile << 7;
  int srl = l >> 2;
  int sq = (l & 3) << 3;               // monotonic source chunk
  const size_t xbase = (size_t)b << 18;

  const u16* wsrc = Wb + (((size_t)(o0 + (w << 4) + srl)) << 10) + sq;
  const u16* xsrc = X + xbase + (((size_t)((w << 4) + srl)) << 10) + sq;

  // stored-chunk byte offsets: czb[h][dc+1] = ((2h + l5) ^ (((l31+dc)>>1)&3)) << 4
  int czb[2][3];
#pragma unroll
  for (int h = 0; h < 2; ++h)
#pragma unroll
    for (int d = 0; d < 3; ++d)
      czb[h][d] = (((2 * h + l5) ^ (((l31 + d - 1) >> 1) & 3)) << 4);
  int pbase[4];
#pragma unroll
  for (int q = 0; q < 4; ++q)
    pbase[q] = (((wm << 7) + (q << 5) + l31) << 6);   // byte row base
  int wrow[2];
#pragma unroll
  for (int n = 0; n < 2; ++n)
    wrow[n] = (((wn << 6) + (n << 5) + l31) << 6);    // byte row base (W)
  const int zo = 256 << 6;   // zero-row (broadcast, conflict-free)

  f32x16 acc[4][2];
#pragma unroll
  for (int q = 0; q < 4; ++q)
#pragma unroll
    for (int n = 0; n < 2; ++n)
#pragma unroll
      for (int e = 0; e < 16; ++e) acc[q][n][e] = 0.f;

  auto stageW = [&](int tap, int kc, int buf) {
    const u16* s = wsrc + (size_t)tap * ((size_t)O << 10) + (kc << 5);
    u16* d0 = &Wlds[buf][(w << 4) << 5];
    gl2lds16(s, d0);
    gl2lds16(s + ((size_t)64 << 10), d0 + (64 << 5));
  };
  auto stageX = [&](int kc, int buf) {
    const u16* s = xsrc + (kc << 5);
    u16* d0 = &Xlds[buf][(w << 4) << 5];
#pragma unroll
    for (int rr = 0; rr < 4; ++rr)
      gl2lds16(s + (((size_t)rr * 64) << 10), d0 + ((rr * 64) << 5));
  };

  if (t < 32) ((unsigned*)&Xlds[t >> 4][256 << 5])[t & 15] = 0u;

  // prologue: X(kc0) -> Xbuf0; W(step0) -> Wlds[0]; W(step1) -> Wlds[1]
  stageX(0, 0);
  stageW(0, 0, 0);
  stageW(1, 0, 1);
  __syncthreads();

  auto kcbody = [&](auto oddc, int kc) {
    constexpr bool ODD = decltype(oddc)::value;
    const char* xb = (const char*)(ODD ? &Xlds[1][0] : &Xlds[0][0]);
#pragma unroll
    for (int tap = 0; tap < 9; ++tap) {
      __builtin_amdgcn_sched_barrier(0);
      // prefetch W for step s+2 (wraps into next kc at taps 7,8)
      {
        int ntap = (tap + 2 > 8) ? (tap - 7) : (tap + 2);
        int nkc = (tap + 2 > 8) ? (kc + 1) : kc;   // tail garbage stays in-ws
        stageW(ntap, nkc, (tap + 2) % 3);
      }
      if (tap == 0) stageX(kc + 1, ODD ? 0 : 1);   // 2 steps of slack before drain
      const char* wbuf = (const char*)&Wlds[tap % 3][0];
      const int dr = tap / 3 - 1, dc = tap % 3 - 1;
      const int dpo = (((dr << 4) + dc) << 6);
#pragma unroll
      for (int h = 0; h < 2; ++h) {
        bf16x8 bw[2], a[4];
#pragma unroll
        for (int n = 0; n < 2; ++n)
          bw[n] = *(const bf16x8*)(wbuf + wrow[n] + czb[h][1]);
#pragma unroll
        for (int q = 0; q < 4; ++q) {
          bool rok = (unsigned)((wm << 3) + (q << 1) + (l31 >> 4) + dr) < 16u;
          bool cok = (unsigned)(px + dc) < 16u;
          int off = (rok & cok) ? (pbase[q] + dpo + czb[h][dc + 1]) : zo;
          a[q] = *(const bf16x8*)(xb + off);
        }
#pragma unroll
        for (int q = 0; q < 4; ++q)
#pragma unroll
          for (int n = 0; n < 2; ++n)
            acc[q][n] = __builtin_amdgcn_mfma_f32_32x32x16_bf16(a[q], bw[n], acc[q][n], 0, 0, 0);
      }
      // FIFO: tap0 entry [Ws1 x2]; +[Ws2 x2, X x4] -> drain Ws1: vmcnt(6)
      //       tap1 entry [Ws2 x2, X x4]; +[Ws3 x2] -> drain Ws2: vmcnt(6)
      //       tap>=2 entry [.., W(s+1) x2]; +[W(s+2) x2] -> keep 2 newest: vmcnt(2)
      if (tap == 0 || tap == 1) asm volatile("s_waitcnt vmcnt(6)" ::: "memory");
      else                      asm volatile("s_waitcnt vmcnt(2)" ::: "memory");
      __builtin_amdgcn_s_barrier();
    }
  };

#pragma unroll 1
  for (int kc2 = 0; kc2 < 16; ++kc2) {
    kcbody(BC<false>{}, 2 * kc2);
    kcbody(BC<true>{}, 2 * kc2 + 1);
  }

  // ---- epilogue: per-wave LDS transpose -> merged swizzled uint4 stores ----
  __syncthreads();   // drains remaining prefetch; LDS reusable
  float bv[2];
#pragma unroll
  for (int n = 0; n < 2; ++n) bv[n] = bias[o0 + (wn << 6) + (n << 5) + l31];
  u16* scr = ((u16*)Xlds) + w * 1152;   // per-wave [16][72] u16 (144B rows)
  int rrow = l >> 2;                    // read-phase: 4 lanes per p-row
  int kq = l & 3;
  int lrow4 = l5 << 2;
#pragma unroll
  for (int q = 0; q < 4; ++q) {
#pragma unroll
    for (int hh = 0; hh < 2; ++hh) {
      // write: regs hh*8+rr -> local row (rr&3)+8*(rr>>2)+4*(l>>5), col n*32+l31
#pragma unroll
      for (int rr = 0; rr < 8; ++rr) {
        int lrow = (rr & 3) + ((rr >> 2) << 3) + lrow4;
#pragma unroll
        for (int n = 0; n < 2; ++n) {
          float vv = acc[q][n][hh * 8 + rr] + bv[n];
          scr[lrow * 72 + (n << 5) + l31] = f2bf(vv > 0.f ? vv : 0.f);
        }
      }
      asm volatile("s_waitcnt lgkmcnt(0)" ::: "memory");
      __builtin_amdgcn_sched_barrier(0);
      // read+store: p = wm*128 + q*32 + hh*16 + (l>>2); 4 lanes cover 128B row seg
      int p = (wm << 7) + (q << 5) + (hh << 4) + rrow;
      int sp = (p >> 1) & 3;
      size_t rbase = (size_t)((b << 8) + p) * O + (size_t)(o0 + (wn << 6));
#pragma unroll
      for (int j = 0; j < 2; ++j) {
        int k = (j << 2) | kq;             // stored chunk (monotone per group)
        int kl = (j << 2) | (kq ^ sp);     // logical chunk held at stored slot k
        uint4 v = *(const uint4*)(scr + rrow * 72 + (kl << 3));
        *(uint4*)(Out + rbase + (k << 3)) = v;
      }
      asm volatile("s_waitcnt lgkmcnt(0)" ::: "memory");
      __builtin_amdgcn_sched_barrier(0);
    }
  }
}

// ---------------------------------------------------------------------------
// Kernel 6: cls head (unchanged from r4; X2 rows in swizzled storage).
__global__ __launch_bounds__(256) void k_cls(const u16* __restrict__ X2,
                                             const float* __restrict__ Wc,
                                             float* __restrict__ out) {
  int b = blockIdx.x, p = threadIdx.x;
  int s = (p >> 1) & 3;
  const uint4* xv = (const uint4*)(X2 + (((size_t)(b << 8) + p) << 9));
  const float4* w0 = (const float4*)(Wc + ((size_t)p << 9));
  const float4* w1 = (const float4*)(Wc + ((size_t)(256 + p) << 9));
  float a0 = 0.f, a1 = 0.f;
#pragma unroll 4
  for (int i = 0; i < 64; ++i) {
    int ii = (i & ~3) | ((i & 3) ^ s);   // stored chunk holding logical chunk i
    uint4 u = xv[ii];
    float x0 = bf2f((u16)(u.x & 0xffffu)), x1 = bf2f((u16)(u.x >> 16));
    float x2 = bf2f((u16)(u.y & 0xffffu)), x3 = bf2f((u16)(u.y >> 16));
    float x4 = bf2f((u16)(u.z & 0xffffu)), x5 = bf2f((u16)(u.z >> 16));
    float x6 = bf2f((u16)(u.w & 0xffffu)), x7 = bf2f((u16)(u.w >> 16));
    float4 wa = w0[i * 2], wb = w0[i * 2 + 1];
    a0 += x0 * wa.x + x1 * wa.y + x2 * wa.z + x3 * wa.w +
          x4 * wb.x + x5 * wb.y + x6 * wb.z + x7 * wb.w;
    float4 wc4 = w1[i * 2], wd = w1[i * 2 + 1];
    a1 += x0 * wc4.x + x1 * wc4.y + x2 * wc4.z + x3 * wc4.w +
          x4 * wd.x + x5 * wd.y + x6 * wd.z + x7 * wd.w;
  }
  a0 = fmaxf(a0, 0.f);
  a1 = fmaxf(a1, 0.f);
  __shared__ float r0[256], r1[256];
  r0[p] = a0; r1[p] = a1;
  for (int sdx = 128; sdx > 0; sdx >>= 1) {
    __syncthreads();
    if (p < sdx) { r0[p] += r0[p + sdx]; r1[p] += r1[p + sdx]; }
  }
  __syncthreads();
  if (p == 0) {
    float s0 = r0[0] * (1.f / 256.f), s1v = r1[0] * (1.f / 256.f);
    float m = fmaxf(s0, s1v);
    float e0 = expf(s0 - m), e1 = expf(s1v - m);
    float inv = 1.f / (e0 + e1);
    out[(b << 1) + 0] = e0 * inv;
    out[(b << 1) + 1] = e1 * inv;
  }
}

// ---------------------------------------------------------------------------
extern "C" void kernel_launch(void* const* d_in, const int* in_sizes, int n_in,
                              void* d_out, int out_size, void* d_ws, size_t ws_size,
                              hipStream_t stream) {
  const float* f1 = (const float*)d_in[0];
  const float* f2 = (const float*)d_in[1];
  const float* w1 = (const float*)d_in[2];
  const float* b1 = (const float*)d_in[3];
  const float* w2 = (const float*)d_in[4];
  const float* b2 = (const float*)d_in[5];
  const float* wc = (const float*)d_in[6];
  float* out = (float*)d_out;
  char* ws = (char*)d_ws;

  u16* featT = (u16*)(ws + 0);
  u16* out1T = (u16*)(ws + 134217728);
  u16* W1b   = (u16*)(ws + 268435456);
  u16* W2b   = (u16*)(ws + 287309824);
  float* s1  = (float*)(ws + 296747008);
  float* s2  = (float*)(ws + 297009152);
  u16* out2T = (u16*)(ws + 0);  // overlays featT (dead after conv1)

  k_norm<<<1024, 256, 0, stream>>>(f1, f2, featT, s1, s2);
  k_wconv<<<1024, 256, 0, stream>>>(w1, W1b, 1024, 1024);
  k_wconv<<<512, 256, 0, stream>>>(w2, W2b, 512, 1024);
  k_corr<<<1024, 256, 0, stream>>>(featT, s1, s2, out);
  k_conv<1024, 3><<<2048, 256, 0, stream>>>(featT, W1b, b1, out1T);
  k_conv<512, 2><<<1024, 256, 0, stream>>>(out1T, W2b, b2, out2T);
  k_cls<<<256, 256, 0, stream>>>(out2T, wc, out);
}